// Round 2
// baseline (3456.183 us; speedup 1.0000x reference)
//
#include <hip/hip_runtime.h>
#include <math.h>

#define HIDDEN 100
#define HEADS 8
#define D 800          // HIDDEN*HEADS
#define ALPHA 0.2f
#define BM 128
#define BN 128
#define KT 16

typedef unsigned short ushort;
typedef unsigned int uint;

__device__ inline float bf2f(ushort u) { uint x = ((uint)u) << 16; return __uint_as_float(x); }
__device__ inline ushort f2bf(float f) {
    uint u = __float_as_uint(f);
    u += 0x7FFF + ((u >> 16) & 1);   // round-to-nearest-even
    return (ushort)(u >> 16);
}

// ---------- CSR row_ptr from sorted src via binary search ----------
__global__ void k_rowptr(const int* __restrict__ src, int E, int n, int* __restrict__ row_ptr) {
    int i = blockIdx.x * blockDim.x + threadIdx.x;
    if (i > n) return;
    int lo = 0, hi = E;
    while (lo < hi) { int mid = (lo + hi) >> 1; if (src[mid] < i) lo = mid + 1; else hi = mid; }
    row_ptr[i] = lo;
}

// ---------- repack kernels (3,8,800,100) -> per-layer (800,800) f32 ----------
__global__ void k_repack(const float* __restrict__ kin, float* __restrict__ kcat) {
    int gid = blockIdx.x * blockDim.x + threadIdx.x;
    if (gid >= 3 * D * D) return;
    int l = gid / (D * D);
    int rem = gid % (D * D);
    int k = rem / D;
    int j = rem % D;
    int h = j / HIDDEN, c = j % HIDDEN;
    kcat[gid] = kin[((size_t)(l * HEADS + h) * D + k) * HIDDEN + c];
}

// ---------- x = relu(ns @ W_pre + b_pre), K=32 ----------
__global__ __launch_bounds__(256) void k_pre(const float* __restrict__ ns, const float* __restrict__ W,
                                             const float* __restrict__ b, float* __restrict__ x, int n) {
    int j = blockIdx.x * 256 + threadIdx.x;
    if (j >= D) return;
    float wk[32];
#pragma unroll
    for (int k = 0; k < 32; k++) wk[k] = W[k * D + j];
    float bj = b[j];
    int r0 = blockIdx.y * 32;
    int r1 = min(r0 + 32, n);
    for (int r = r0; r < r1; r++) {
        float acc = bj;
#pragma unroll
        for (int k = 0; k < 32; k++) acc += ns[r * 32 + k] * wk[k];
        x[(size_t)r * D + j] = fmaxf(acc, 0.f);
    }
}

// ---------- Ht[M x 800](bf16) = A[M x 800](f32) @ B[800 x 800](f32) ----------
__global__ __launch_bounds__(256) void k_gemm(const float* __restrict__ A, const float* __restrict__ B,
                                              ushort* __restrict__ C, int M) {
    __shared__ float As[KT][BM + 4];   // transposed A tile: As[k][row]
    __shared__ float Bs[KT][BN + 4];
    int tid = threadIdx.x;
    int tx = tid & 15, ty = tid >> 4;
    int row0 = blockIdx.y * BM;
    int col0 = blockIdx.x * BN;
    float acc[8][8] = {};
    int arow = tid >> 1;          // 0..127
    int ak   = (tid & 1) * 8;     // 0 or 8
    int bk   = tid >> 4;          // 0..15
    int bcol = (tid & 15) * 8;    // 0..120

    for (int k0 = 0; k0 < D; k0 += KT) {
        int garow = row0 + arow; garow = garow < M ? garow : M - 1;
        const float* ap = A + (size_t)garow * D + k0 + ak;
        float4 a0 = *(const float4*)ap;
        float4 a1 = *(const float4*)(ap + 4);
        int gbc = col0 + bcol; gbc = gbc < D ? gbc : D - 8;
        const float* bp = B + (size_t)(k0 + bk) * D + gbc;
        float4 b0 = *(const float4*)bp;
        float4 b1 = *(const float4*)(bp + 4);
        __syncthreads();
        float av[8] = {a0.x, a0.y, a0.z, a0.w, a1.x, a1.y, a1.z, a1.w};
#pragma unroll
        for (int q = 0; q < 8; q++) As[ak + q][arow] = av[q];
        *(float4*)&Bs[bk][bcol] = b0;
        *(float4*)&Bs[bk][bcol + 4] = b1;
        __syncthreads();
#pragma unroll
        for (int k = 0; k < KT; k++) {
            float4 p0 = *(const float4*)&As[k][ty * 8];
            float4 p1 = *(const float4*)&As[k][ty * 8 + 4];
            float4 q0 = *(const float4*)&Bs[k][tx * 8];
            float4 q1 = *(const float4*)&Bs[k][tx * 8 + 4];
            float ar[8] = {p0.x, p0.y, p0.z, p0.w, p1.x, p1.y, p1.z, p1.w};
            float br[8] = {q0.x, q0.y, q0.z, q0.w, q1.x, q1.y, q1.z, q1.w};
#pragma unroll
            for (int i = 0; i < 8; i++)
#pragma unroll
                for (int j = 0; j < 8; j++) acc[i][j] += ar[i] * br[j];
        }
    }
    int c = col0 + tx * 8;
    if (c < D) {
#pragma unroll
        for (int i = 0; i < 8; i++) {
            int r = row0 + ty * 8 + i;
            if (r >= M) continue;
            union { ushort u[8]; uint4 v; } pk;
#pragma unroll
            for (int q = 0; q < 8; q++) pk.u[q] = f2bf(acc[i][q]);
            *(uint4*)(C + (size_t)r * D + c) = pk.v;
        }
    }
}

// ---------- s,t per (node, head) from bf16 Ht ----------
__global__ __launch_bounds__(256) void k_st(const ushort* __restrict__ Ht, const float* __restrict__ att_l,
                                            float* __restrict__ s_all, float* __restrict__ t_all, int n) {
    int gid = blockIdx.x * blockDim.x + threadIdx.x;
    if (gid >= n * HEADS) return;
    int i = gid >> 3, h = gid & 7;
    const uint2* hp2 = (const uint2*)(Ht + (size_t)i * D + h * HIDDEN);   // 8B aligned (200h % 8 == 0)
    const float* As = att_l + h * 2 * HIDDEN;
    const float* At = As + HIDDEN;
    float s = 0.f, t = 0.f;
#pragma unroll 5
    for (int q = 0; q < 25; q++) {
        uint2 v = hp2[q];
        float f0 = bf2f((ushort)(v.x & 0xFFFF)), f1 = bf2f((ushort)(v.x >> 16));
        float f2 = bf2f((ushort)(v.y & 0xFFFF)), f3 = bf2f((ushort)(v.y >> 16));
        int c = q * 4;
        s += f0 * As[c] + f1 * As[c + 1] + f2 * As[c + 2] + f3 * As[c + 3];
        t += f0 * At[c] + f1 * At[c + 1] + f2 * At[c + 2] + f3 * At[c + 3];
    }
    s_all[gid] = s;
    t_all[gid] = t;
}

// ---------- per-node segment softmax + aggregate + relu + residual (x in-place) ----------
__global__ __launch_bounds__(256) void k_edge(const ushort* __restrict__ Ht, float* __restrict__ x,
                                              const float* __restrict__ s_all, const float* __restrict__ t_all,
                                              const int* __restrict__ dst, const int* __restrict__ row_ptr,
                                              int n) {
    int i = blockIdx.x;
    int t = threadIdx.x;
    __shared__ float lw[32][8];
    __shared__ int ld[32];
    int e0 = row_ptr[i], e1 = row_ptr[i + 1];
    int c0 = t, c1 = t + 256, c2 = t + 512, c3 = t + 768;   // c3 valid iff t<32
    int h0 = c0 / HIDDEN, h1 = c1 / HIDDEN, h2 = c2 / HIDDEN;
    float acc0 = 0, acc1 = 0, acc2 = 0, acc3 = 0;
    float den0 = 0, den1 = 0, den2 = 0, den3 = 0;
    int el = t >> 3, hh = t & 7;
    float s_ih = s_all[i * 8 + hh];

    for (int base = e0; base < e1; base += 32) {
        int cnt = min(32, e1 - base);
        __syncthreads();   // protect LDS reuse from previous chunk
        if (el < cnt) {
            int d = dst[base + el];
            float ev = s_ih + t_all[d * 8 + hh];
            ev = ev >= 0.f ? ev : ALPHA * ev;
            ev = fminf(fmaxf(ev, -2.f), 2.f);
            lw[el][hh] = __expf(ev);
            if (hh == 0) ld[el] = d;
        }
        __syncthreads();
        for (int e = 0; e < cnt; e++) {
            int d = ld[e];
            const ushort* hp = Ht + (size_t)d * D;
            float w0 = lw[e][h0], w1 = lw[e][h1], w2 = lw[e][h2];
            acc0 += w0 * bf2f(hp[c0]); den0 += w0;
            acc1 += w1 * bf2f(hp[c1]); den1 += w1;
            acc2 += w2 * bf2f(hp[c2]); den2 += w2;
            if (t < 32) {
                float w3 = lw[e][7];
                acc3 += w3 * bf2f(hp[c3]); den3 += w3;
            }
        }
    }
    float* xr = x + (size_t)i * D;
    xr[c0] = (den0 > 0.f ? fmaxf(acc0 / den0, 0.f) : 0.f) + xr[c0];
    xr[c1] = (den1 > 0.f ? fmaxf(acc1 / den1, 0.f) : 0.f) + xr[c1];
    xr[c2] = (den2 > 0.f ? fmaxf(acc2 / den2, 0.f) : 0.f) + xr[c2];
    if (t < 32) xr[c3] = (den3 > 0.f ? fmaxf(acc3 / den3, 0.f) : 0.f) + xr[c3];
}

// ---------- final stage A: per-block partial of sum_i (x_i . Wl + bl) * Wc_i ----------
__global__ __launch_bounds__(256) void k_final(const float* __restrict__ x, const float* __restrict__ Wl,
                                               const float* __restrict__ bl, const float* __restrict__ Wc,
                                               float* __restrict__ fpart, int n) {
    __shared__ float part[4];
    int lane = threadIdx.x & 63, w = threadIdx.x >> 6;
    int wid = blockIdx.x * 4 + w;
    int nw = gridDim.x * 4;
    float p = 0.f;
    for (int i = wid; i < n; i += nw) {
        float dot = 0.f;
#pragma unroll
        for (int r = 0; r < 13; r++) {
            int j = r * 64 + lane;
            if (j < D) dot += x[(size_t)i * D + j] * Wl[j];
        }
#pragma unroll
        for (int off = 32; off; off >>= 1) dot += __shfl_xor(dot, off);
        if (lane == 0) p += (dot + bl[0]) * Wc[i];
    }
    if (lane == 0) part[w] = p;
    __syncthreads();
    if (threadIdx.x == 0) fpart[blockIdx.x] = part[0] + part[1] + part[2] + part[3];
}

// ---------- final stage B: reduce partials + bc -> d_out ----------
__global__ __launch_bounds__(128) void k_reduce(const float* __restrict__ fpart, const float* __restrict__ bc,
                                                float* __restrict__ out, int nb) {
    int t = threadIdx.x;
    float v = (t < nb) ? fpart[t] : 0.f;
#pragma unroll
    for (int off = 64; off; off >>= 1) v += __shfl_xor(v, off, 128) * 0.f + v * 0.f + __shfl_xor(v, off);
    // (the line above would double-count; do a clean reduction instead)
    if (t == 0) {
        float s = 0.f;
        for (int q = 0; q < nb; q++) s += fpart[q];
        out[0] = s + bc[0];
    }
}

// ---------- sentinel if workspace too small ----------
__global__ void k_sentinel(float* out) { out[0] = 12345.0f; }

extern "C" void kernel_launch(void* const* d_in, const int* in_sizes, int n_in,
                              void* d_out, int out_size, void* d_ws, size_t ws_size,
                              hipStream_t stream) {
    const float* ns   = (const float*)d_in[0];
    const int*   src  = (const int*)d_in[1];
    const int*   dst  = (const int*)d_in[2];
    const float* Wpre = (const float*)d_in[3];
    const float* bpre = (const float*)d_in[4];
    const float* kern = (const float*)d_in[5];
    const float* att  = (const float*)d_in[6];
    const float* Wl   = (const float*)d_in[7];
    const float* bl   = (const float*)d_in[8];
    const float* Wc   = (const float*)d_in[9];
    const float* bc   = (const float*)d_in[10];
    int n = in_sizes[9];   // Wc has n elements
    int E = in_sizes[1];

    size_t need = 0;
    auto sz = [&](size_t bytes) { size_t o = need; need += (bytes + 255) & ~255ull; return o; };
    size_t o_x     = sz((size_t)n * D * 4);          // f32 x, in-place across layers
    size_t o_Ht    = sz((size_t)n * D * 2);          // bf16 Ht
    size_t o_kcat  = sz(3ull * D * D * 4);
    size_t o_s     = sz((size_t)n * 8 * 4);
    size_t o_t     = sz((size_t)n * 8 * 4);
    size_t o_rp    = sz(((size_t)n + 1) * 4);
    size_t o_fp    = sz(128 * 4);

    if (need > ws_size) {   // diagnostic: absmax will be ~12345
        k_sentinel<<<1, 1, 0, stream>>>((float*)d_out);
        return;
    }

    char* ws = (char*)d_ws;
    float*  x     = (float*)(ws + o_x);
    ushort* Ht    = (ushort*)(ws + o_Ht);
    float*  kcat  = (float*)(ws + o_kcat);
    float*  s_all = (float*)(ws + o_s);
    float*  t_all = (float*)(ws + o_t);
    int*    row_ptr = (int*)(ws + o_rp);
    float*  fpart = (float*)(ws + o_fp);

    k_rowptr<<<(n + 1 + 255) / 256, 256, 0, stream>>>(src, E, n, row_ptr);
    k_repack<<<(3 * D * D + 255) / 256, 256, 0, stream>>>(kern, kcat);
    dim3 gpre((D + 255) / 256, (n + 31) / 32);
    k_pre<<<gpre, 256, 0, stream>>>(ns, Wpre, bpre, x, n);

    for (int l = 0; l < 3; l++) {
        dim3 gg((D + BN - 1) / BN, (n + BM - 1) / BM);
        k_gemm<<<gg, 256, 0, stream>>>(x, kcat + (size_t)l * D * D, Ht, n);
        k_st<<<(n * HEADS + 255) / 256, 256, 0, stream>>>(Ht, att + l * HEADS * 2 * HIDDEN, s_all, t_all, n);
        k_edge<<<n, 256, 0, stream>>>(Ht, x, s_all, t_all, dst, row_ptr, n);
    }

    k_final<<<120, 256, 0, stream>>>(x, Wl, bl, Wc, fpart, n);
    k_reduce<<<1, 128, 0, stream>>>(fpart, bc, (float*)d_out, 120);
}

// Round 4
// 2274.369 us; speedup vs baseline: 1.5196x; 1.5196x over previous
//
#include <hip/hip_runtime.h>
#include <math.h>

#define HIDDEN 100
#define HEADS 8
#define D 800          // HIDDEN*HEADS
#define ALPHA 0.2f

typedef unsigned short ushort;
typedef unsigned int uint;
typedef __attribute__((ext_vector_type(8))) short bf16x8;
typedef __attribute__((ext_vector_type(4))) float f32x4;

__device__ inline float bf2f(ushort u) { uint x = ((uint)u) << 16; return __uint_as_float(x); }
__device__ inline ushort f2bf(float f) {
    uint u = __float_as_uint(f);
    u += 0x7FFF + ((u >> 16) & 1);   // round-to-nearest-even
    return (ushort)(u >> 16);
}

// ---------- CSR row_ptr from sorted src via binary search ----------
__global__ void k_rowptr(const int* __restrict__ src, int E, int n, int* __restrict__ row_ptr) {
    int i = blockIdx.x * blockDim.x + threadIdx.x;
    if (i > n) return;
    int lo = 0, hi = E;
    while (lo < hi) { int mid = (lo + hi) >> 1; if (src[mid] < i) lo = mid + 1; else hi = mid; }
    row_ptr[i] = lo;
}

// ---------- repack kernels (3,8,800,100) -> per-layer transposed split bf16 ----------
// Bsp layout: [layer][2(hi,lo)][n=800][k=800] bf16, Bt[n][k] = kin[l, n/100, k, n%100]
__global__ void k_repack(const float* __restrict__ kin, ushort* __restrict__ bsp) {
    int gid = blockIdx.x * blockDim.x + threadIdx.x;
    if (gid >= 3 * D * D) return;
    int l = gid / (D * D);
    int rem = gid % (D * D);
    int nn = rem / D;        // output col (n)
    int k = rem % D;         // output row in k
    int h = nn / HIDDEN, c = nn % HIDDEN;
    float v = kin[((size_t)(l * HEADS + h) * D + k) * HIDDEN + c];
    ushort hi = f2bf(v);
    ushort lo = f2bf(v - bf2f(hi));
    size_t base = ((size_t)l * 2 * D + nn) * D + k;
    bsp[base] = hi;
    bsp[base + (size_t)D * D] = lo;
}

// ---------- x = relu(ns @ W_pre + b_pre), K=32 ----------
__global__ __launch_bounds__(256) void k_pre(const float* __restrict__ ns, const float* __restrict__ W,
                                             const float* __restrict__ b, float* __restrict__ x, int n) {
    int j = blockIdx.x * 256 + threadIdx.x;
    if (j >= D) return;
    float wk[32];
#pragma unroll
    for (int k = 0; k < 32; k++) wk[k] = W[k * D + j];
    float bj = b[j];
    int r0 = blockIdx.y * 32;
    int r1 = min(r0 + 32, n);
    for (int r = r0; r < r1; r++) {
        float acc = bj;
#pragma unroll
        for (int k = 0; k < 32; k++) acc += ns[r * 32 + k] * wk[k];
        x[(size_t)r * D + j] = fmaxf(acc, 0.f);
    }
}

// ---------- Ht[M x 800](bf16) = A[M x 800](f32) @ B[800 x 800], MFMA 3-pass compensated ----------
// BM=128 BN=160 BK=32; 4 waves (2x2); dbuf LDS; B pre-split/transposed (Bsp)
__global__ __launch_bounds__(256) void k_gemm(const float* __restrict__ A, const ushort* __restrict__ Bsp,
                                              ushort* __restrict__ C, int M) {
    __shared__ __align__(16) ushort Ah[2][128][32];
    __shared__ __align__(16) ushort Al[2][128][32];
    __shared__ __align__(16) ushort Bh[2][160][32];
    __shared__ __align__(16) ushort Bl[2][160][32];

    const ushort* Bh_g = Bsp;
    const ushort* Bl_g = Bsp + (size_t)D * D;
    int row0 = blockIdx.y * 128, col0 = blockIdx.x * 160;
    int t = threadIdx.x;

    // A staging: thread -> (row, 16-wide k chunk)
    int ar = t >> 1, akh = (t & 1) * 16;
    int garow = min(row0 + ar, M - 1);
    const float* aptr = A + (size_t)garow * D + akh;

    float areg[16];
    uint4 bregh[3], bregl[3];

    auto loadA = [&](int k0) {
        const float4* p = (const float4*)(aptr + k0);
#pragma unroll
        for (int q = 0; q < 4; q++) *(float4*)&areg[q * 4] = p[q];
    };
    auto loadB = [&](int k0) {
#pragma unroll
        for (int j = 0; j < 3; j++) {
            int c = t + j * 256;
            if (c < 640) {
                int nn = c >> 2, kq = c & 3;
                size_t go = (size_t)(col0 + nn) * D + k0 + kq * 8;
                bregh[j] = *(const uint4*)&Bh_g[go];
                bregl[j] = *(const uint4*)&Bl_g[go];
            }
        }
    };
    auto writeAB = [&](int buf) {
        uint hi[8], lo[8];
#pragma unroll
        for (int q = 0; q < 8; q++) {
            float f0 = areg[2 * q], f1 = areg[2 * q + 1];
            ushort h0 = f2bf(f0), h1 = f2bf(f1);
            ushort l0 = f2bf(f0 - bf2f(h0)), l1 = f2bf(f1 - bf2f(h1));
            hi[q] = (uint)h0 | ((uint)h1 << 16);
            lo[q] = (uint)l0 | ((uint)l1 << 16);
        }
        *(uint4*)&Ah[buf][ar][akh]     = make_uint4(hi[0], hi[1], hi[2], hi[3]);
        *(uint4*)&Ah[buf][ar][akh + 8] = make_uint4(hi[4], hi[5], hi[6], hi[7]);
        *(uint4*)&Al[buf][ar][akh]     = make_uint4(lo[0], lo[1], lo[2], lo[3]);
        *(uint4*)&Al[buf][ar][akh + 8] = make_uint4(lo[4], lo[5], lo[6], lo[7]);
#pragma unroll
        for (int j = 0; j < 3; j++) {
            int c = t + j * 256;
            if (c < 640) {
                int nn = c >> 2, kq = c & 3;
                *(uint4*)&Bh[buf][nn][kq * 8] = bregh[j];
                *(uint4*)&Bl[buf][nn][kq * 8] = bregl[j];
            }
        }
    };

    int w = t >> 6, lane = t & 63;
    int wr = w >> 1, wc = w & 1;
    int l15 = lane & 15, ks = lane >> 4;
    f32x4 acc[4][5] = {};

    auto compute = [&](int buf) {
        bf16x8 bh[5], bl[5];
#pragma unroll
        for (int ni = 0; ni < 5; ni++) {
            int col = wc * 80 + ni * 16 + l15;
            bh[ni] = *(const bf16x8*)&Bh[buf][col][ks * 8];
            bl[ni] = *(const bf16x8*)&Bl[buf][col][ks * 8];
        }
#pragma unroll
        for (int mi = 0; mi < 4; mi++) {
            int row = wr * 64 + mi * 16 + l15;
            bf16x8 ah = *(const bf16x8*)&Ah[buf][row][ks * 8];
            bf16x8 al = *(const bf16x8*)&Al[buf][row][ks * 8];
#pragma unroll
            for (int ni = 0; ni < 5; ni++) {
                acc[mi][ni] = __builtin_amdgcn_mfma_f32_16x16x32_bf16(ah, bh[ni], acc[mi][ni], 0, 0, 0);
                acc[mi][ni] = __builtin_amdgcn_mfma_f32_16x16x32_bf16(al, bh[ni], acc[mi][ni], 0, 0, 0);
                acc[mi][ni] = __builtin_amdgcn_mfma_f32_16x16x32_bf16(ah, bl[ni], acc[mi][ni], 0, 0, 0);
            }
        }
    };

    loadA(0); loadB(0);
    writeAB(0);
    __syncthreads();
    const int NT = D / 32;   // 25
    for (int tt = 0; tt < NT; tt++) {
        if (tt + 1 < NT) { loadA((tt + 1) * 32); loadB((tt + 1) * 32); }
        compute(tt & 1);
        if (tt + 1 < NT) writeAB((tt + 1) & 1);
        __syncthreads();
    }

    // C/D layout: col = lane&15, row = (lane>>4)*4 + r   [m89-verified]
#pragma unroll
    for (int mi = 0; mi < 4; mi++) {
#pragma unroll
        for (int ni = 0; ni < 5; ni++) {
            int gr0 = row0 + wr * 64 + mi * 16 + ks * 4;
            int gc = col0 + wc * 80 + ni * 16 + l15;
#pragma unroll
            for (int r = 0; r < 4; r++) {
                int gr = gr0 + r;
                if (gr < M) C[(size_t)gr * D + gc] = f2bf(acc[mi][ni][r]);
            }
        }
    }
}

// ---------- s,t per (node, head) from bf16 Ht ----------
__global__ __launch_bounds__(256) void k_st(const ushort* __restrict__ Ht, const float* __restrict__ att_l,
                                            float* __restrict__ s_all, float* __restrict__ t_all, int n) {
    int gid = blockIdx.x * blockDim.x + threadIdx.x;
    if (gid >= n * HEADS) return;
    int i = gid >> 3, h = gid & 7;
    const uint2* hp2 = (const uint2*)(Ht + (size_t)i * D + h * HIDDEN);
    const float* As = att_l + h * 2 * HIDDEN;
    const float* At = As + HIDDEN;
    float s = 0.f, t = 0.f;
#pragma unroll 5
    for (int q = 0; q < 25; q++) {
        uint2 v = hp2[q];
        float f0 = bf2f((ushort)(v.x & 0xFFFF)), f1 = bf2f((ushort)(v.x >> 16));
        float f2 = bf2f((ushort)(v.y & 0xFFFF)), f3 = bf2f((ushort)(v.y >> 16));
        int c = q * 4;
        s += f0 * As[c] + f1 * As[c + 1] + f2 * As[c + 2] + f3 * As[c + 3];
        t += f0 * At[c] + f1 * At[c + 1] + f2 * At[c + 2] + f3 * At[c + 3];
    }
    s_all[gid] = s;
    t_all[gid] = t;
}

// ---------- per-node segment softmax + aggregate + relu + residual (x in-place) ----------
// threads 0..255 compute edge weights (32/chunk); threads 0..199 aggregate 4 bf16 each
__global__ __launch_bounds__(256) void k_edge(const ushort* __restrict__ Ht, float* __restrict__ x,
                                              const float* __restrict__ s_all, const float* __restrict__ t_all,
                                              const int* __restrict__ dst, const int* __restrict__ row_ptr,
                                              int n) {
    int i = blockIdx.x;
    int t = threadIdx.x;
    __shared__ float lw[32][8];
    __shared__ int ld[32];
    int e0 = row_ptr[i], e1 = row_ptr[i + 1];
    int h = t / 25;            // head for aggregation (valid for t<200)
    int el = t >> 3, hh = t & 7;
    float s_ih = s_all[i * 8 + hh];
    float acc0 = 0, acc1 = 0, acc2 = 0, acc3 = 0, den = 0;

    for (int base = e0; base < e1; base += 32) {
        int cnt = min(32, e1 - base);
        __syncthreads();
        if (el < cnt) {
            int d = dst[base + el];
            float ev = s_ih + t_all[d * 8 + hh];
            ev = ev >= 0.f ? ev : ALPHA * ev;
            ev = fminf(fmaxf(ev, -2.f), 2.f);
            lw[el][hh] = __expf(ev);
            if (hh == 0) ld[el] = d;
        }
        __syncthreads();
        if (t < 200) {
#pragma unroll 4
            for (int e = 0; e < cnt; e++) {
                int d = ld[e];
                uint2 v = *(const uint2*)(Ht + (size_t)d * D + t * 4);
                float wgt = lw[e][h];
                acc0 += wgt * bf2f((ushort)(v.x & 0xFFFF));
                acc1 += wgt * bf2f((ushort)(v.x >> 16));
                acc2 += wgt * bf2f((ushort)(v.y & 0xFFFF));
                acc3 += wgt * bf2f((ushort)(v.y >> 16));
                den += wgt;
            }
        }
    }
    if (t < 200) {
        float* xr = x + (size_t)i * D + t * 4;
        float4 xv = *(float4*)xr;
        float inv = den > 0.f ? 1.f / den : 0.f;
        xv.x += fmaxf(acc0 * inv, 0.f);
        xv.y += fmaxf(acc1 * inv, 0.f);
        xv.z += fmaxf(acc2 * inv, 0.f);
        xv.w += fmaxf(acc3 * inv, 0.f);
        *(float4*)xr = xv;
    }
}

// ---------- final stage A: per-block partial of sum_i (x_i . Wl + bl) * Wc_i ----------
__global__ __launch_bounds__(256) void k_final(const float* __restrict__ x, const float* __restrict__ Wl,
                                               const float* __restrict__ bl, const float* __restrict__ Wc,
                                               float* __restrict__ fpart, int n) {
    __shared__ float part[4];
    int lane = threadIdx.x & 63, w = threadIdx.x >> 6;
    int wid = blockIdx.x * 4 + w;
    int nw = gridDim.x * 4;
    float p = 0.f;
    for (int i = wid; i < n; i += nw) {
        float dot = 0.f;
#pragma unroll
        for (int r = 0; r < 13; r++) {
            int j = r * 64 + lane;
            if (j < D) dot += x[(size_t)i * D + j] * Wl[j];
        }
#pragma unroll
        for (int off = 32; off; off >>= 1) dot += __shfl_xor(dot, off);
        if (lane == 0) p += (dot + bl[0]) * Wc[i];
    }
    if (lane == 0) part[w] = p;
    __syncthreads();
    if (threadIdx.x == 0) fpart[blockIdx.x] = part[0] + part[1] + part[2] + part[3];
}

// ---------- final stage B ----------
__global__ __launch_bounds__(64) void k_reduce(const float* __restrict__ fpart, const float* __restrict__ bc,
                                               float* __restrict__ out, int nb) {
    if (threadIdx.x == 0) {
        float s = 0.f;
        for (int q = 0; q < nb; q++) s += fpart[q];
        out[0] = s + bc[0];
    }
}

// ---------- sentinel if workspace too small ----------
__global__ void k_sentinel(float* out) { out[0] = 12345.0f; }

extern "C" void kernel_launch(void* const* d_in, const int* in_sizes, int n_in,
                              void* d_out, int out_size, void* d_ws, size_t ws_size,
                              hipStream_t stream) {
    const float* ns   = (const float*)d_in[0];
    const int*   src  = (const int*)d_in[1];
    const int*   dst  = (const int*)d_in[2];
    const float* Wpre = (const float*)d_in[3];
    const float* bpre = (const float*)d_in[4];
    const float* kern = (const float*)d_in[5];
    const float* att  = (const float*)d_in[6];
    const float* Wl   = (const float*)d_in[7];
    const float* bl   = (const float*)d_in[8];
    const float* Wc   = (const float*)d_in[9];
    const float* bc   = (const float*)d_in[10];
    int n = in_sizes[9];   // Wc has n elements
    int E = in_sizes[1];

    size_t need = 0;
    auto sz = [&](size_t bytes) { size_t o = need; need += (bytes + 255) & ~255ull; return o; };
    size_t o_x     = sz((size_t)n * D * 4);          // f32 x, in-place across layers
    size_t o_Ht    = sz((size_t)n * D * 2);          // bf16 Ht
    size_t o_bsp   = sz(3ull * 2 * D * D * 2);       // bf16 split+transposed weights
    size_t o_s     = sz((size_t)n * 8 * 4);
    size_t o_t     = sz((size_t)n * 8 * 4);
    size_t o_rp    = sz(((size_t)n + 1) * 4);
    size_t o_fp    = sz(128 * 4);

    if (need > ws_size) {   // diagnostic: absmax will be ~12345
        k_sentinel<<<1, 1, 0, stream>>>((float*)d_out);
        return;
    }

    char* ws = (char*)d_ws;
    float*  x     = (float*)(ws + o_x);
    ushort* Ht    = (ushort*)(ws + o_Ht);
    ushort* bsp   = (ushort*)(ws + o_bsp);
    float*  s_all = (float*)(ws + o_s);
    float*  t_all = (float*)(ws + o_t);
    int*    row_ptr = (int*)(ws + o_rp);
    float*  fpart = (float*)(ws + o_fp);

    k_rowptr<<<(n + 1 + 255) / 256, 256, 0, stream>>>(src, E, n, row_ptr);
    k_repack<<<(3 * D * D + 255) / 256, 256, 0, stream>>>(kern, bsp);
    dim3 gpre((D + 255) / 256, (n + 31) / 32);
    k_pre<<<gpre, 256, 0, stream>>>(ns, Wpre, bpre, x, n);

    for (int l = 0; l < 3; l++) {
        dim3 gg(D / 160, (n + 127) / 128);
        k_gemm<<<gg, 256, 0, stream>>>(x, bsp + (size_t)l * 2 * D * D, Ht, n);
        k_st<<<(n * HEADS + 255) / 256, 256, 0, stream>>>(Ht, att + l * HEADS * 2 * HIDDEN, s_all, t_all, n);
        k_edge<<<n, 256, 0, stream>>>(Ht, x, s_all, t_all, dst, row_ptr, n);
    }

    k_final<<<120, 256, 0, stream>>>(x, Wl, bl, Wc, fpart, n);
    k_reduce<<<1, 64, 0, stream>>>(fpart, bc, (float*)d_out, 120);
}

// Round 5
// 1657.258 us; speedup vs baseline: 2.0855x; 1.3724x over previous
//
#include <hip/hip_runtime.h>
#include <math.h>

#define HIDDEN 100
#define HEADS 8
#define D 800          // HIDDEN*HEADS
#define ALPHA 0.2f

typedef unsigned short ushort;
typedef unsigned int uint;
typedef __attribute__((ext_vector_type(8))) short bf16x8;
typedef __attribute__((ext_vector_type(4))) float f32x4;

__device__ inline float bf2f(ushort u) { uint x = ((uint)u) << 16; return __uint_as_float(x); }
__device__ inline ushort f2bf(float f) {
    uint u = __float_as_uint(f);
    u += 0x7FFF + ((u >> 16) & 1);   // round-to-nearest-even
    return (ushort)(u >> 16);
}

// async global->LDS, 16B per lane; LDS dest = wave-uniform base + lane*16
__device__ inline void gl_lds16(const void* g, void* l) {
    __builtin_amdgcn_global_load_lds((const __attribute__((address_space(1))) void*)g,
                                     (__attribute__((address_space(3))) void*)l, 16, 0, 0);
}

// ---------- CSR row_ptr from sorted src via binary search ----------
__global__ void k_rowptr(const int* __restrict__ src, int E, int n, int* __restrict__ row_ptr) {
    int i = blockIdx.x * blockDim.x + threadIdx.x;
    if (i > n) return;
    int lo = 0, hi = E;
    while (lo < hi) { int mid = (lo + hi) >> 1; if (src[mid] < i) lo = mid + 1; else hi = mid; }
    row_ptr[i] = lo;
}

// ---------- repack kernels (3,8,800,100) -> per-layer transposed split bf16 ----------
// Bsp layout: [layer][2(hi,lo)][n=800][k=800] bf16, Bt[n][k] = kin[l, n/100, k, n%100]
__global__ void k_repack(const float* __restrict__ kin, ushort* __restrict__ bsp) {
    int gid = blockIdx.x * blockDim.x + threadIdx.x;
    if (gid >= 3 * D * D) return;
    int l = gid / (D * D);
    int rem = gid % (D * D);
    int nn = rem / D;        // output col (n)
    int k = rem % D;         // output row in k
    int h = nn / HIDDEN, c = nn % HIDDEN;
    float v = kin[((size_t)(l * HEADS + h) * D + k) * HIDDEN + c];
    ushort hi = f2bf(v);
    ushort lo = f2bf(v - bf2f(hi));
    size_t base = ((size_t)l * 2 * D + nn) * D + k;
    bsp[base] = hi;
    bsp[base + (size_t)D * D] = lo;
}

// ---------- x = relu(ns @ W_pre + b_pre), K=32 ----------
__global__ __launch_bounds__(256) void k_pre(const float* __restrict__ ns, const float* __restrict__ W,
                                             const float* __restrict__ b, float* __restrict__ x, int n) {
    int j = blockIdx.x * 256 + threadIdx.x;
    if (j >= D) return;
    float wk[32];
#pragma unroll
    for (int k = 0; k < 32; k++) wk[k] = W[k * D + j];
    float bj = b[j];
    int r0 = blockIdx.y * 32;
    int r1 = min(r0 + 32, n);
    for (int r = r0; r < r1; r++) {
        float acc = bj;
#pragma unroll
        for (int k = 0; k < 32; k++) acc += ns[r * 32 + k] * wk[k];
        x[(size_t)r * D + j] = fmaxf(acc, 0.f);
    }
}

// ---------- Ht[M x 800](bf16) = A[M x 800](f32) @ B[800 x 800], MFMA 3-pass compensated ----------
// BM=128 BN=160 BK=32; 4 waves (2x2); single LDS buffer, fragment-ordered (conflict-free);
// B staged via global_load_lds; XCD-aware block swizzle (5 col-blocks of a row share an XCD).
__global__ __launch_bounds__(256) void k_gemm(const float* __restrict__ A, const ushort* __restrict__ Bsp,
                                              ushort* __restrict__ C, int M) {
    // fragment-ordered: tile stride 512 ushorts (1024B); within tile: ks*128 + l15*8 == lane*8
    __shared__ __align__(16) ushort Af[2 * 8 * 512];    // hi tiles 0..7, lo tiles 8..15 (16 KB)
    __shared__ __align__(16) ushort Bf[2 * 10 * 512];   // hi tiles 0..9, lo tiles 10..19 (20 KB)

    int d = blockIdx.x;
    int q = d & 7, m = d >> 3;      // XCD swizzle: blocks with same row-block land on same XCD (d%8)
    int c = m % 5, j = m / 5;
    int r = j * 8 + q;
    int nrb = (M + 127) >> 7;
    if (r >= nrb) return;
    int row0 = r * 128, col0 = c * 160;

    int t = threadIdx.x;
    int w = t >> 6, lane = t & 63;
    int wr = w >> 1, wc = w & 1;
    int bl15 = lane & 15, bks = lane >> 4;

    // A staging: thread -> row ar (0..127), 16-wide k half
    int ar = t >> 1, kh = (t & 1) * 16;
    int garow = min(row0 + ar, M - 1);
    const float* aptr = A + (size_t)garow * D + kh;
    int ta = ar >> 4, al15 = ar & 15, ks0 = kh >> 3;
    ushort* ahd = &Af[ta * 512 + ks0 * 128 + al15 * 8];       // hi, ks0
    ushort* ald = ahd + 8 * 512;                              // lo region

    f32x4 acc[4][5] = {};

    for (int kt = 0; kt < 25; kt++) {
        int k0 = kt * 32;
        __syncthreads();           // previous tile's compute done; LDS reusable
        // ---- B: 20 chunks (10 hi + 10 lo), 5 per wave, each = one 16-col x 32-k tile ----
#pragma unroll
        for (int i = 0; i < 5; i++) {
            int g = i * 4 + w;
            int mat = (g >= 10) ? 1 : 0;
            int tile = g - mat * 10;
            const ushort* src = Bsp + (size_t)mat * D * D
                              + (size_t)(col0 + tile * 16 + bl15) * D + k0 + bks * 8;
            gl_lds16(src, &Bf[(mat * 10 + tile) * 512]);
        }
        // ---- A: load 16 f32, split hi/lo, write fragment-ordered ----
        float4 a0 = *(const float4*)(aptr + k0);
        float4 a1 = *(const float4*)(aptr + k0 + 4);
        float4 a2 = *(const float4*)(aptr + k0 + 8);
        float4 a3 = *(const float4*)(aptr + k0 + 12);
        float av[16] = {a0.x, a0.y, a0.z, a0.w, a1.x, a1.y, a1.z, a1.w,
                        a2.x, a2.y, a2.z, a2.w, a3.x, a3.y, a3.z, a3.w};
        uint hi[8], lo[8];
#pragma unroll
        for (int p = 0; p < 8; p++) {
            float f0 = av[2 * p], f1 = av[2 * p + 1];
            ushort h0 = f2bf(f0), h1 = f2bf(f1);
            ushort l0 = f2bf(f0 - bf2f(h0)), l1 = f2bf(f1 - bf2f(h1));
            hi[p] = (uint)h0 | ((uint)h1 << 16);
            lo[p] = (uint)l0 | ((uint)l1 << 16);
        }
        *(uint4*)ahd         = make_uint4(hi[0], hi[1], hi[2], hi[3]);
        *(uint4*)(ahd + 128) = make_uint4(hi[4], hi[5], hi[6], hi[7]);
        *(uint4*)ald         = make_uint4(lo[0], lo[1], lo[2], lo[3]);
        *(uint4*)(ald + 128) = make_uint4(lo[4], lo[5], lo[6], lo[7]);
        __syncthreads();           // staging (incl. global_load_lds) complete
        // ---- compute: all fragment reads are wave-contiguous 1024B -> conflict-free ----
        bf16x8 bh[5], bl[5];
#pragma unroll
        for (int ni = 0; ni < 5; ni++) {
            int tb = wc * 5 + ni;
            bh[ni] = *(const bf16x8*)&Bf[tb * 512 + lane * 8];
            bl[ni] = *(const bf16x8*)&Bf[(10 + tb) * 512 + lane * 8];
        }
#pragma unroll
        for (int mi = 0; mi < 4; mi++) {
            int tA = wr * 4 + mi;
            bf16x8 ah = *(const bf16x8*)&Af[tA * 512 + lane * 8];
            bf16x8 al = *(const bf16x8*)&Af[(8 + tA) * 512 + lane * 8];
#pragma unroll
            for (int ni = 0; ni < 5; ni++) {
                acc[mi][ni] = __builtin_amdgcn_mfma_f32_16x16x32_bf16(ah, bh[ni], acc[mi][ni], 0, 0, 0);
                acc[mi][ni] = __builtin_amdgcn_mfma_f32_16x16x32_bf16(al, bh[ni], acc[mi][ni], 0, 0, 0);
                acc[mi][ni] = __builtin_amdgcn_mfma_f32_16x16x32_bf16(ah, bl[ni], acc[mi][ni], 0, 0, 0);
            }
        }
    }

    // C/D layout: col = lane&15, row = (lane>>4)*4 + reg   [m89-verified]
#pragma unroll
    for (int mi = 0; mi < 4; mi++) {
#pragma unroll
        for (int ni = 0; ni < 5; ni++) {
            int gr0 = row0 + wr * 64 + mi * 16 + bks * 4;
            int gc = col0 + wc * 80 + ni * 16 + bl15;
#pragma unroll
            for (int rr = 0; rr < 4; rr++) {
                int gr = gr0 + rr;
                if (gr < M) C[(size_t)gr * D + gc] = f2bf(acc[mi][ni][rr]);
            }
        }
    }
}

// ---------- s,t per (node, head) from bf16 Ht ----------
__global__ __launch_bounds__(256) void k_st(const ushort* __restrict__ Ht, const float* __restrict__ att_l,
                                            float* __restrict__ s_all, float* __restrict__ t_all, int n) {
    int gid = blockIdx.x * blockDim.x + threadIdx.x;
    if (gid >= n * HEADS) return;
    int i = gid >> 3, h = gid & 7;
    const uint2* hp2 = (const uint2*)(Ht + (size_t)i * D + h * HIDDEN);
    const float* As = att_l + h * 2 * HIDDEN;
    const float* At = As + HIDDEN;
    float s = 0.f, t = 0.f;
#pragma unroll 5
    for (int q = 0; q < 25; q++) {
        uint2 v = hp2[q];
        float f0 = bf2f((ushort)(v.x & 0xFFFF)), f1 = bf2f((ushort)(v.x >> 16));
        float f2 = bf2f((ushort)(v.y & 0xFFFF)), f3 = bf2f((ushort)(v.y >> 16));
        int c = q * 4;
        s += f0 * As[c] + f1 * As[c + 1] + f2 * As[c + 2] + f3 * As[c + 3];
        t += f0 * At[c] + f1 * At[c + 1] + f2 * At[c + 2] + f3 * At[c + 3];
    }
    s_all[gid] = s;
    t_all[gid] = t;
}

// ---------- per-node segment softmax + aggregate + relu + residual (x in-place) ----------
__global__ __launch_bounds__(256) void k_edge(const ushort* __restrict__ Ht, float* __restrict__ x,
                                              const float* __restrict__ s_all, const float* __restrict__ t_all,
                                              const int* __restrict__ dst, const int* __restrict__ row_ptr,
                                              int n) {
    int i = blockIdx.x;
    int t = threadIdx.x;
    __shared__ float lw[32][8];
    __shared__ int ld[32];
    int e0 = row_ptr[i], e1 = row_ptr[i + 1];
    int h = t / 25;            // head for aggregation (valid for t<200)
    int el = t >> 3, hh = t & 7;
    float s_ih = s_all[i * 8 + hh];
    float acc0 = 0, acc1 = 0, acc2 = 0, acc3 = 0, den = 0;

    for (int base = e0; base < e1; base += 32) {
        int cnt = min(32, e1 - base);
        __syncthreads();
        if (el < cnt) {
            int d = dst[base + el];
            float ev = s_ih + t_all[d * 8 + hh];
            ev = ev >= 0.f ? ev : ALPHA * ev;
            ev = fminf(fmaxf(ev, -2.f), 2.f);
            lw[el][hh] = __expf(ev);
            if (hh == 0) ld[el] = d;
        }
        __syncthreads();
        if (t < 200) {
#pragma unroll 4
            for (int e = 0; e < cnt; e++) {
                int d = ld[e];
                uint2 v = *(const uint2*)(Ht + (size_t)d * D + t * 4);
                float wgt = lw[e][h];
                acc0 += wgt * bf2f((ushort)(v.x & 0xFFFF));
                acc1 += wgt * bf2f((ushort)(v.x >> 16));
                acc2 += wgt * bf2f((ushort)(v.y & 0xFFFF));
                acc3 += wgt * bf2f((ushort)(v.y >> 16));
                den += wgt;
            }
        }
    }
    if (t < 200) {
        float* xr = x + (size_t)i * D + t * 4;
        float4 xv = *(float4*)xr;
        float inv = den > 0.f ? 1.f / den : 0.f;
        xv.x += fmaxf(acc0 * inv, 0.f);
        xv.y += fmaxf(acc1 * inv, 0.f);
        xv.z += fmaxf(acc2 * inv, 0.f);
        xv.w += fmaxf(acc3 * inv, 0.f);
        *(float4*)xr = xv;
    }
}

// ---------- final stage A: per-block partial of sum_i (x_i . Wl + bl) * Wc_i ----------
__global__ __launch_bounds__(256) void k_final(const float* __restrict__ x, const float* __restrict__ Wl,
                                               const float* __restrict__ bl, const float* __restrict__ Wc,
                                               float* __restrict__ fpart, int n) {
    __shared__ float part[4];
    int lane = threadIdx.x & 63, w = threadIdx.x >> 6;
    int wid = blockIdx.x * 4 + w;
    int nw = gridDim.x * 4;
    float p = 0.f;
    for (int i = wid; i < n; i += nw) {
        float dot = 0.f;
#pragma unroll
        for (int r = 0; r < 13; r++) {
            int j = r * 64 + lane;
            if (j < D) dot += x[(size_t)i * D + j] * Wl[j];
        }
#pragma unroll
        for (int off = 32; off; off >>= 1) dot += __shfl_xor(dot, off);
        if (lane == 0) p += (dot + bl[0]) * Wc[i];
    }
    if (lane == 0) part[w] = p;
    __syncthreads();
    if (threadIdx.x == 0) fpart[blockIdx.x] = part[0] + part[1] + part[2] + part[3];
}

// ---------- final stage B ----------
__global__ __launch_bounds__(64) void k_reduce(const float* __restrict__ fpart, const float* __restrict__ bc,
                                               float* __restrict__ out, int nb) {
    if (threadIdx.x == 0) {
        float s = 0.f;
        for (int q = 0; q < nb; q++) s += fpart[q];
        out[0] = s + bc[0];
    }
}

// ---------- sentinel if workspace too small ----------
__global__ void k_sentinel(float* out) { out[0] = 12345.0f; }

extern "C" void kernel_launch(void* const* d_in, const int* in_sizes, int n_in,
                              void* d_out, int out_size, void* d_ws, size_t ws_size,
                              hipStream_t stream) {
    const float* ns   = (const float*)d_in[0];
    const int*   src  = (const int*)d_in[1];
    const int*   dst  = (const int*)d_in[2];
    const float* Wpre = (const float*)d_in[3];
    const float* bpre = (const float*)d_in[4];
    const float* kern = (const float*)d_in[5];
    const float* att  = (const float*)d_in[6];
    const float* Wl   = (const float*)d_in[7];
    const float* bl   = (const float*)d_in[8];
    const float* Wc   = (const float*)d_in[9];
    const float* bc   = (const float*)d_in[10];
    int n = in_sizes[9];   // Wc has n elements
    int E = in_sizes[1];

    size_t need = 0;
    auto sz = [&](size_t bytes) { size_t o = need; need += (bytes + 255) & ~255ull; return o; };
    size_t o_x     = sz((size_t)n * D * 4);          // f32 x, in-place across layers
    size_t o_Ht    = sz((size_t)n * D * 2);          // bf16 Ht
    size_t o_bsp   = sz(3ull * 2 * D * D * 2);       // bf16 split+transposed weights
    size_t o_s     = sz((size_t)n * 8 * 4);
    size_t o_t     = sz((size_t)n * 8 * 4);
    size_t o_rp    = sz(((size_t)n + 1) * 4);
    size_t o_fp    = sz(128 * 4);

    if (need > ws_size) {   // diagnostic: absmax will be ~12345
        k_sentinel<<<1, 1, 0, stream>>>((float*)d_out);
        return;
    }

    char* ws = (char*)d_ws;
    float*  x     = (float*)(ws + o_x);
    ushort* Ht    = (ushort*)(ws + o_Ht);
    ushort* bsp   = (ushort*)(ws + o_bsp);
    float*  s_all = (float*)(ws + o_s);
    float*  t_all = (float*)(ws + o_t);
    int*    row_ptr = (int*)(ws + o_rp);
    float*  fpart = (float*)(ws + o_fp);

    k_rowptr<<<(n + 1 + 255) / 256, 256, 0, stream>>>(src, E, n, row_ptr);
    k_repack<<<(3 * D * D + 255) / 256, 256, 0, stream>>>(kern, bsp);
    dim3 gpre((D + 255) / 256, (n + 31) / 32);
    k_pre<<<gpre, 256, 0, stream>>>(ns, Wpre, bpre, x, n);

    int nrb = (n + 127) / 128;                    // 391 row blocks
    int grid_g = 8 * (((nrb + 7) / 8) * 5);       // 1960: swizzle-decoded inside kernel
    for (int l = 0; l < 3; l++) {
        k_gemm<<<grid_g, 256, 0, stream>>>(x, bsp + (size_t)l * 2 * D * D, Ht, n);
        k_st<<<(n * HEADS + 255) / 256, 256, 0, stream>>>(Ht, att + l * HEADS * 2 * HIDDEN, s_all, t_all, n);
        k_edge<<<n, 256, 0, stream>>>(Ht, x, s_all, t_all, dst, row_ptr, n);
    }

    k_final<<<120, 256, 0, stream>>>(x, Wl, bl, Wc, fpart, n);
    k_reduce<<<1, 64, 0, stream>>>(fpart, bc, (float*)d_out, 120);
}